// Round 1
// baseline (340.555 us; speedup 1.0000x reference)
//
#include <hip/hip_runtime.h>

#define NOUT 7
#define NROI 512
#define NCH 256
#define CSPLIT 2
#define CPB (NCH / CSPLIT)   // channels per block = 128
#define BINS (NOUT * NOUT)   // 49

__global__ __launch_bounds__(256) void roi_pool_kernel(
    const float* __restrict__ x2,
    const float* __restrict__ x3,
    const float* __restrict__ x4,
    const float* __restrict__ x5,
    const float* __restrict__ boxes,
    float* __restrict__ out)
{
    const int r  = blockIdx.x;   // roi 0..511
    const int cs = blockIdx.y;   // channel split 0..CSPLIT-1
    const int t  = threadIdx.x;  // 0..255

    __shared__ int   sy0W[14], sy1W[14];
    __shared__ int   sx0[14], sx1[14];
    __shared__ float sfy[14], smy[14];   // smy = 0.25 * valid_y  (fold SRxSR mean)
    __shared__ float sfx[14], smx[14];   // smx = valid_x
    __shared__ const float* sbase;       // feat + b*C*H*W
    __shared__ int sHW;

    if (t < 32) {
        const float bx1 = boxes[4 * r + 0];
        const float by1 = boxes[4 * r + 1];
        const float bx2 = boxes[4 * r + 2];
        const float by2 = boxes[4 * r + 3];
        const float sz  = sqrtf((bx2 - bx1) * (by2 - by1));
        float lvlf = floorf(4.0f + log2f(sz / 224.0f + 1e-8f));
        lvlf = fminf(fmaxf(lvlf, 2.0f), 5.0f);
        const int level = (int)lvlf - 2;

        int H, W; float scale; const float* feat;
        if (level == 0)      { H = 200; W = 304; scale = 0.25f;    feat = x2; }
        else if (level == 1) { H = 100; W = 152; scale = 0.125f;   feat = x3; }
        else if (level == 2) { H = 50;  W = 76;  scale = 0.0625f;  feat = x4; }
        else                 { H = 25;  W = 38;  scale = 0.03125f; feat = x5; }

        const float X1 = bx1 * scale - 0.5f;
        const float Y1 = by1 * scale - 0.5f;
        const float X2 = bx2 * scale - 0.5f;
        const float Y2 = by2 * scale - 0.5f;
        const float bw = (X2 - X1) * (1.0f / NOUT);
        const float bh = (Y2 - Y1) * (1.0f / NOUT);

        if (t < 14) {
            // y-axis sample t
            const float g = 0.25f + 0.5f * (float)t;
            float c = Y1 + g * bh;
            const bool valid = (c >= -1.0f) && (c <= (float)H);
            c = fminf(fmaxf(c, 0.0f), (float)(H - 1));
            const float c0 = floorf(c);
            const int i0 = (int)c0;
            const int i1 = min(i0 + 1, H - 1);
            sy0W[t] = i0 * W;
            sy1W[t] = i1 * W;
            sfy[t]  = c - c0;
            smy[t]  = valid ? 0.25f : 0.0f;
        } else if (t >= 16 && t < 30) {
            // x-axis sample k
            const int k = t - 16;
            const float g = 0.25f + 0.5f * (float)k;
            float c = X1 + g * bw;
            const bool valid = (c >= -1.0f) && (c <= (float)W);
            c = fminf(fmaxf(c, 0.0f), (float)(W - 1));
            const float c0 = floorf(c);
            const int i0 = (int)c0;
            const int i1 = min(i0 + 1, W - 1);
            sx0[k] = i0;
            sx1[k] = i1;
            sfx[k] = c - c0;
            smx[k] = valid ? 1.0f : 0.0f;
        } else if (t == 31) {
            const int b = r >> 8;
            sbase = feat + (size_t)b * NCH * H * W;
            sHW   = H * W;
        }
    }
    __syncthreads();

    const float* const base = sbase;
    const int HW = sHW;
    const int c0base = cs * CPB;
    float* const outr = out + (size_t)r * (NCH * BINS) + (size_t)c0base * BINS;

    for (int i = t; i < CPB * BINS; i += 256) {
        const int c   = i / BINS;
        const int bin = i - c * BINS;
        const int ph  = bin / NOUT;
        const int pw  = bin - ph * NOUT;
        const float* const f = base + (size_t)(c0base + c) * HW;

        float acc = 0.0f;
        #pragma unroll
        for (int sy = 0; sy < 2; ++sy) {
            const int j = ph * 2 + sy;
            const int y0W = sy0W[j];
            const int y1W = sy1W[j];
            const float fy = sfy[j];
            const float wy = smy[j];
            #pragma unroll
            for (int sx = 0; sx < 2; ++sx) {
                const int ii = pw * 2 + sx;
                const int x0 = sx0[ii];
                const int x1 = sx1[ii];
                const float fx = sfx[ii];
                const float wx = smx[ii];
                const float v00 = f[y0W + x0];
                const float v01 = f[y0W + x1];
                const float v10 = f[y1W + x0];
                const float v11 = f[y1W + x1];
                const float top = v00 + (v10 - v00) * fy;
                const float bot = v01 + (v11 - v01) * fy;
                const float bil = top + (bot - top) * fx;
                acc += wy * wx * bil;
            }
        }
        outr[i] = acc;
    }
}

extern "C" void kernel_launch(void* const* d_in, const int* in_sizes, int n_in,
                              void* d_out, int out_size, void* d_ws, size_t ws_size,
                              hipStream_t stream) {
    const float* x2    = (const float*)d_in[0];
    const float* x3    = (const float*)d_in[1];
    const float* x4    = (const float*)d_in[2];
    const float* x5    = (const float*)d_in[3];
    const float* boxes = (const float*)d_in[4];
    float* out = (float*)d_out;

    dim3 grid(NROI, CSPLIT);
    roi_pool_kernel<<<grid, 256, 0, stream>>>(x2, x3, x4, x5, boxes, out);
}

// Round 2
// 255.741 us; speedup vs baseline: 1.3316x; 1.3316x over previous
//
#include <hip/hip_runtime.h>

#define NOUT 7
#define NROI 512
#define NCH 256
#define BINS (NOUT * NOUT)        // 49
#define ROI_ELEMS (NCH * BINS)    // 12544
#define CHUNKS (ROI_ELEMS / 256)  // 49 blocks of 256 threads per roi

__global__ __launch_bounds__(256) void roi_pool_kernel(
    const float* __restrict__ x2,
    const float* __restrict__ x3,
    const float* __restrict__ x4,
    const float* __restrict__ x5,
    const float* __restrict__ boxes,
    float* __restrict__ out)
{
    const int r     = blockIdx.x;  // roi 0..511
    const int chunk = blockIdx.y;  // 0..48
    const int t     = threadIdx.x; // 0..255

    __shared__ int   sy0W[14], sy1W[14];
    __shared__ int   sx0[14], sx1[14];
    __shared__ float sfy[14], smy[14];   // smy = 0.25 * valid_y (folds SRxSR mean)
    __shared__ float sfx[14], smx[14];   // smx = valid_x
    __shared__ const float* sbase;       // feat + b*C*H*W
    __shared__ int sHW;

    if (t < 32) {
        const float bx1 = boxes[4 * r + 0];
        const float by1 = boxes[4 * r + 1];
        const float bx2 = boxes[4 * r + 2];
        const float by2 = boxes[4 * r + 3];
        const float sz  = sqrtf((bx2 - bx1) * (by2 - by1));
        float lvlf = floorf(4.0f + log2f(sz / 224.0f + 1e-8f));
        lvlf = fminf(fmaxf(lvlf, 2.0f), 5.0f);
        const int level = (int)lvlf - 2;

        int H, W; float scale; const float* feat;
        if (level == 0)      { H = 200; W = 304; scale = 0.25f;    feat = x2; }
        else if (level == 1) { H = 100; W = 152; scale = 0.125f;   feat = x3; }
        else if (level == 2) { H = 50;  W = 76;  scale = 0.0625f;  feat = x4; }
        else                 { H = 25;  W = 38;  scale = 0.03125f; feat = x5; }

        const float X1 = bx1 * scale - 0.5f;
        const float Y1 = by1 * scale - 0.5f;
        const float X2 = bx2 * scale - 0.5f;
        const float Y2 = by2 * scale - 0.5f;
        const float bw = (X2 - X1) * (1.0f / NOUT);
        const float bh = (Y2 - Y1) * (1.0f / NOUT);

        if (t < 14) {
            // y-axis sample t
            const float g = 0.25f + 0.5f * (float)t;
            float c = Y1 + g * bh;
            const bool valid = (c >= -1.0f) && (c <= (float)H);
            c = fminf(fmaxf(c, 0.0f), (float)(H - 1));
            const float c0 = floorf(c);
            const int i0 = (int)c0;
            const int i1 = min(i0 + 1, H - 1);
            sy0W[t] = i0 * W;
            sy1W[t] = i1 * W;
            sfy[t]  = c - c0;
            smy[t]  = valid ? 0.25f : 0.0f;
        } else if (t >= 16 && t < 30) {
            // x-axis sample k
            const int k = t - 16;
            const float g = 0.25f + 0.5f * (float)k;
            float c = X1 + g * bw;
            const bool valid = (c >= -1.0f) && (c <= (float)W);
            c = fminf(fmaxf(c, 0.0f), (float)(W - 1));
            const float c0 = floorf(c);
            const int i0 = (int)c0;
            const int i1 = min(i0 + 1, W - 1);
            sx0[k] = i0;
            sx1[k] = i1;
            sfx[k] = c - c0;
            smx[k] = valid ? 1.0f : 0.0f;
        } else if (t == 31) {
            const int b = r >> 8;
            sbase = feat + (size_t)b * NCH * H * W;
            sHW   = H * W;
        }
    }
    __syncthreads();

    const float* const base = sbase;
    const int HW = sHW;

    // one output element per thread
    const int i   = chunk * 256 + t;      // 0..12543 within this roi
    const int c   = i / BINS;             // channel 0..255
    const int bin = i - c * BINS;         // 0..48
    const int ph  = bin / NOUT;
    const int pw  = bin - ph * NOUT;
    const float* const f = base + (size_t)c * HW;

    float acc = 0.0f;
    #pragma unroll
    for (int sy = 0; sy < 2; ++sy) {
        const int j = ph * 2 + sy;
        const int y0W = sy0W[j];
        const int y1W = sy1W[j];
        const float fy = sfy[j];
        const float wy = smy[j];
        #pragma unroll
        for (int sx = 0; sx < 2; ++sx) {
            const int ii = pw * 2 + sx;
            const int x0 = sx0[ii];
            const int x1 = sx1[ii];
            const float fx = sfx[ii];
            const float wx = smx[ii];
            const float v00 = f[y0W + x0];
            const float v01 = f[y0W + x1];
            const float v10 = f[y1W + x0];
            const float v11 = f[y1W + x1];
            const float top = v00 + (v10 - v00) * fy;
            const float bot = v01 + (v11 - v01) * fy;
            const float bil = top + (bot - top) * fx;
            acc += wy * wx * bil;
        }
    }
    out[(size_t)r * ROI_ELEMS + i] = acc;
}

extern "C" void kernel_launch(void* const* d_in, const int* in_sizes, int n_in,
                              void* d_out, int out_size, void* d_ws, size_t ws_size,
                              hipStream_t stream) {
    const float* x2    = (const float*)d_in[0];
    const float* x3    = (const float*)d_in[1];
    const float* x4    = (const float*)d_in[2];
    const float* x5    = (const float*)d_in[3];
    const float* boxes = (const float*)d_in[4];
    float* out = (float*)d_out;

    dim3 grid(NROI, CHUNKS);
    roi_pool_kernel<<<grid, 256, 0, stream>>>(x2, x3, x4, x5, boxes, out);
}

// Round 3
// 225.317 us; speedup vs baseline: 1.5115x; 1.1350x over previous
//
#include <hip/hip_runtime.h>

#define NOUT 7
#define NROI 512
#define NCH 256
#define BINS (NOUT * NOUT)        // 49
#define ROI_ELEMS (NCH * BINS)    // 12544
#define CHUNKS (ROI_ELEMS / 256)  // 49 blocks of 256 threads per roi

__global__ __launch_bounds__(256) void roi_pool_kernel(
    const float* __restrict__ x2,
    const float* __restrict__ x3,
    const float* __restrict__ x4,
    const float* __restrict__ x5,
    const float* __restrict__ boxes,
    float* __restrict__ out)
{
    const int r     = blockIdx.x;  // roi 0..511
    const int chunk = blockIdx.y;  // 0..48
    const int t     = threadIdx.x; // 0..255

    // Descriptors packed for ds_read_b128:
    //  sdy[j] = { asfloat(y0*W), fy, wy(=0.25*valid_y), 0 }   (y1 == y0+1 always)
    //  sdx[k] = { asfloat(x0),   fx, wx(=valid_x),      0 }   (x1 == x0+1 always)
    __shared__ float4 sdy[14];
    __shared__ float4 sdx[14];
    __shared__ const float* sbase;   // feat + b*C*H*W
    __shared__ int sHW, sW;

    if (t < 32) {
        const float bx1 = boxes[4 * r + 0];
        const float by1 = boxes[4 * r + 1];
        const float bx2 = boxes[4 * r + 2];
        const float by2 = boxes[4 * r + 3];
        const float sz  = sqrtf((bx2 - bx1) * (by2 - by1));
        float lvlf = floorf(4.0f + log2f(sz / 224.0f + 1e-8f));
        lvlf = fminf(fmaxf(lvlf, 2.0f), 5.0f);
        const int level = (int)lvlf - 2;

        int H, W; float scale; const float* feat;
        if (level == 0)      { H = 200; W = 304; scale = 0.25f;    feat = x2; }
        else if (level == 1) { H = 100; W = 152; scale = 0.125f;   feat = x3; }
        else if (level == 2) { H = 50;  W = 76;  scale = 0.0625f;  feat = x4; }
        else                 { H = 25;  W = 38;  scale = 0.03125f; feat = x5; }

        const float X1 = bx1 * scale - 0.5f;
        const float Y1 = by1 * scale - 0.5f;
        const float X2 = bx2 * scale - 0.5f;
        const float Y2 = by2 * scale - 0.5f;
        const float bw = (X2 - X1) * (1.0f / NOUT);
        const float bh = (Y2 - Y1) * (1.0f / NOUT);

        if (t < 14) {
            // y-axis sample t.  Normalize so y1 = y0+1 always:
            // if floor(c)==H-1 (only when c==H-1 exactly), use y0=H-2, fy=1.
            const float g = 0.25f + 0.5f * (float)t;
            float c = Y1 + g * bh;
            const bool valid = (c >= -1.0f) && (c <= (float)H);
            c = fminf(fmaxf(c, 0.0f), (float)(H - 1));
            int i0 = (int)floorf(c);
            i0 = min(i0, H - 2);
            sdy[t] = make_float4(__int_as_float(i0 * W),
                                 c - (float)i0,
                                 valid ? 0.25f : 0.0f,
                                 0.0f);
        } else if (t >= 16 && t < 30) {
            // x-axis sample k, same normalization: x1 = x0+1 always.
            const int k = t - 16;
            const float g = 0.25f + 0.5f * (float)k;
            float c = X1 + g * bw;
            const bool valid = (c >= -1.0f) && (c <= (float)W);
            c = fminf(fmaxf(c, 0.0f), (float)(W - 1));
            int i0 = (int)floorf(c);
            i0 = min(i0, W - 2);
            sdx[k] = make_float4(__int_as_float(i0),
                                 c - (float)i0,
                                 valid ? 1.0f : 0.0f,
                                 0.0f);
        } else if (t == 31) {
            const int b = r >> 8;
            sbase = feat + (size_t)b * NCH * H * W;
            sHW   = H * W;
            sW    = W;
        }
    }
    __syncthreads();

    const float* const base = sbase;
    const int HW = sHW;
    const int W  = sW;

    // one output element per thread
    const int i   = chunk * 256 + t;      // 0..12543 within this roi
    const int c   = i / BINS;             // channel 0..255
    const int bin = i - c * BINS;         // 0..48
    const int ph  = bin / NOUT;
    const int pw  = bin - ph * NOUT;
    const float* const f = base + (size_t)c * HW;

    const float4 dy0 = sdy[ph * 2 + 0];
    const float4 dy1 = sdy[ph * 2 + 1];
    const float4 dx0 = sdx[pw * 2 + 0];
    const float4 dx1 = sdx[pw * 2 + 1];

    float acc = 0.0f;
    #pragma unroll
    for (int sy = 0; sy < 2; ++sy) {
        const float4 dy = sy ? dy1 : dy0;
        const int   y0W = __float_as_int(dy.x);
        const float fy  = dy.y;
        const float wy  = dy.z;
        const float* const row0 = f + y0W;
        const float* const row1 = row0 + W;
        #pragma unroll
        for (int sx = 0; sx < 2; ++sx) {
            const float4 dx = sx ? dx1 : dx0;
            const int   x0 = __float_as_int(dx.x);
            const float fx = dx.y;
            const float wx = dx.z;
            // 2x2 patch as two 8B loads (dword-aligned; gfx950 supports
            // unaligned global dwordx2)
            const float2 a0 = *(const float2*)(row0 + x0);
            const float2 a1 = *(const float2*)(row1 + x0);
            const float top = a0.x + (a0.y - a0.x) * fx;
            const float bot = a1.x + (a1.y - a1.x) * fx;
            const float bil = top + (bot - top) * fy;
            acc += wy * wx * bil;
        }
    }
    out[(size_t)r * ROI_ELEMS + i] = acc;
}

extern "C" void kernel_launch(void* const* d_in, const int* in_sizes, int n_in,
                              void* d_out, int out_size, void* d_ws, size_t ws_size,
                              hipStream_t stream) {
    const float* x2    = (const float*)d_in[0];
    const float* x3    = (const float*)d_in[1];
    const float* x4    = (const float*)d_in[2];
    const float* x5    = (const float*)d_in[3];
    const float* boxes = (const float*)d_in[4];
    float* out = (float*)d_out;

    dim3 grid(NROI, CHUNKS);
    roi_pool_kernel<<<grid, 256, 0, stream>>>(x2, x3, x4, x5, boxes, out);
}